// Round 1
// baseline (462.297 us; speedup 1.0000x reference)
//
#include <hip/hip_runtime.h>

// LSTM: B=8192, T=512, IN=8, H=64, OUT=1
// R6: critical-path restructure.
//   - x-gate MFMAs (a2 term) hoisted OUT of the h-dependency chain: xacc[g]
//     for step t+1 is computed pre-barrier of step t (xlds is chunk-stable,
//     no h dependence) -> post-barrier chain is ds_read(a0,a1) + 2 dep MFMAs.
//   - chunk-top barrier removed: staging write (opposite xlds parity) folded
//     into step 0's shadow, publication by the regular step barrier; global
//     prefetch reissued at step 1. 512+1 barriers total (was 544+).
// R5: transcendental diet. c kept in scaled domain chat = 2log2e*c:
//   chat' = [chat*(1+A)(1+G) + K(G-1)(1+F)] * rcp((1+F)(1+A)(1+G))
//   h     = (C-1) * rcp((1+O)(1+C)),  C = 2^chat'
//   (A=2^ai_acc, G=2^ag_acc, F=2^af_acc, O=2^ao_acc) -> 5 exp2 + 2 rcp per
//   element. Bias lives in persistent MFMA C-operand regs.
// R4: x staged through double-buffered LDS in 16-step chunks (no inner vmem).
// R2: activation scale folded into weights (-log2e for i/f/o, +2log2e for g).
// Wave w owns hidden units [16w,16w+16). h double-buffered through LDS (f16).
// MFMA layouts (m89/m91/m120 verified):
//   A[m=lane&15][k=(lane>>4)*8+j], B[k=(lane>>4)*8+j][n=lane&15],
//   C/D: col=lane&15, row=(lane>>4)*4+reg.

typedef _Float16 f16_t;
typedef _Float16 half8 __attribute__((ext_vector_type(8)));
typedef __fp16 fp16x2 __attribute__((ext_vector_type(2)));
typedef float floatx2 __attribute__((ext_vector_type(2)));
typedef float floatx4 __attribute__((ext_vector_type(4)));

#define Bn 8192
#define Tn 512
#define INn 8
#define Hn 64
#define BT 16
#define CHUNK 16
#define NCHUNK (Tn / CHUNK)
#define HSTRIDE 72    // f16; 36 words -> a0/a1 b128 reads 2-way (free)
#define XTSTRIDE 136  // f16 per tt: 16 rows * 8 + 8 pad; 68 words -> 4-bank skew

__device__ __forceinline__ floatx2 act_pair(float zi0, float zi1,
                                            float zf0, float zf1,
                                            float zg0, float zg1,
                                            float zo0, float zo1,
                                            floatx2& chat) {
  const floatx2 one  = {1.f, 1.f};
  const float  K2   = 2.8853900817779268f;  // 2*log2(e)
  const floatx2 K2v  = {K2, K2};
  const floatx2 mK2v = {-K2, -K2};
  const floatx2 clmp = {126.f, 126.f};
  floatx2 A = {__builtin_amdgcn_exp2f(zi0), __builtin_amdgcn_exp2f(zi1)};
  floatx2 G = {__builtin_amdgcn_exp2f(zg0), __builtin_amdgcn_exp2f(zg1)};
  floatx2 F = {__builtin_amdgcn_exp2f(zf0), __builtin_amdgcn_exp2f(zf1)};
  floatx2 O = {__builtin_amdgcn_exp2f(zo0), __builtin_amdgcn_exp2f(zo1)};
  floatx2 PA  = A + one;
  floatx2 PG  = G + one;
  floatx2 PF  = F + one;
  floatx2 PAG = PA * PG;
  floatx2 num = __builtin_elementwise_fma(G, K2v, mK2v) * PF;  // K(G-1)(1+F)
  floatx2 s   = __builtin_elementwise_fma(chat, PAG, num);
  floatx2 P3  = PF * PAG;
  floatx2 R   = {__builtin_amdgcn_rcpf(P3.x), __builtin_amdgcn_rcpf(P3.y)};
  chat = __builtin_elementwise_min(s * R, clmp);
  floatx2 C2 = {__builtin_amdgcn_exp2f(chat.x), __builtin_amdgcn_exp2f(chat.y)};
  floatx2 P4 = (O + one) * (C2 + one);
  floatx2 Rh = {__builtin_amdgcn_rcpf(P4.x), __builtin_amdgcn_rcpf(P4.y)};
  return (C2 - one) * Rh;  // h = o * tanh(c)
}

__global__ __launch_bounds__(256, 2)
void lstm_fused(const float* __restrict__ xg,
                const float* __restrict__ W_ih,
                const float* __restrict__ W_hh,
                const float* __restrict__ b_ih,
                const float* __restrict__ b_hh,
                const float* __restrict__ W_fc,
                const float* __restrict__ b_fc,
                float* __restrict__ out)
{
  __shared__ alignas(16) f16_t hbuf[2][BT][HSTRIDE];
  __shared__ alignas(16) f16_t xlds[2][CHUNK][XTSTRIDE];

  const int tid   = threadIdx.x;
  const int wv    = tid >> 6;     // wave 0..3 -> hidden units 16w..16w+15
  const int lane  = tid & 63;
  const int n     = lane & 15;    // A-row (batch) / B-col / D-col index
  const int q     = lane >> 4;    // quad
  const int bbase = blockIdx.x * BT;

  const float LOG2E = 1.4426950408889634f;

  // ---- B fragments (weights), pre-scaled, resident in VGPRs/AGPRs.
  // Gate g in {i,f,g,o}: column C = 64*g + 16*wv + n.
  // K layout: k in [0,64) = W_hh cols, [64,72) = W_ih cols, [72,96) = 0.
  half8 bf[4][3];
  #pragma unroll
  for (int g = 0; g < 4; ++g) {
    const float sc = (g == 2) ? (2.f * LOG2E) : (-LOG2E);
    const int C = g * 64 + wv * 16 + n;
    #pragma unroll
    for (int c = 0; c < 3; ++c) {
      half8 v;
      #pragma unroll
      for (int j = 0; j < 8; ++j) {
        const int k = c * 32 + q * 8 + j;
        float w = 0.f;
        if (k < Hn)            w = W_hh[C * Hn + k] * sc;
        else if (k < Hn + INn) w = W_ih[C * INn + (k - Hn)] * sc;
        v[j] = (f16_t)w;
      }
      bf[g][c] = v;
    }
  }

  // ---- scaled biases -> persistent MFMA C-operand registers
  const int u = wv * 16 + n;  // this lane's hidden unit (acc column)
  const float pb_i = -(b_ih[u]       + b_hh[u])       * LOG2E;
  const float pb_f = -(b_ih[64 + u]  + b_hh[64 + u])  * LOG2E;
  const float pb_g =  (b_ih[128 + u] + b_hh[128 + u]) * (2.f * LOG2E);
  const float pb_o = -(b_ih[192 + u] + b_hh[192 + u]) * LOG2E;
  const floatx4 bi  = {pb_i, pb_i, pb_i, pb_i};
  const floatx4 bfv = {pb_f, pb_f, pb_f, pb_f};
  const floatx4 bg  = {pb_g, pb_g, pb_g, pb_g};
  const floatx4 bo  = {pb_o, pb_o, pb_o, pb_o};

  // ---- LDS init: h0 = 0 in hbuf[0]
  for (int i = tid; i < BT * HSTRIDE; i += 256) ((f16_t*)hbuf[0])[i] = (f16_t)0.f;

  // ---- x staging assignment: lane -> (row, tt); 16-lane groups coalesce 512B
  const int row_s = tid >> 4;   // 0..15 batch row
  const int tt_s  = tid & 15;   // 0..15 timestep within chunk
  const float* xps = xg + ((size_t)(bbase + row_s) * Tn + tt_s) * INn;

  // ---- stage chunk 0 straight into xlds[0]
  {
    float4 a  = *(const float4*)(xps);
    float4 b2 = *(const float4*)(xps + 4);
    union { half8 v; fp16x2 h2[4]; } P;
    P.h2[0] = __builtin_amdgcn_cvt_pkrtz(a.x, a.y);
    P.h2[1] = __builtin_amdgcn_cvt_pkrtz(a.z, a.w);
    P.h2[2] = __builtin_amdgcn_cvt_pkrtz(b2.x, b2.y);
    P.h2[3] = __builtin_amdgcn_cvt_pkrtz(b2.z, b2.w);
    *(half8*)&xlds[0][tt_s][row_s * 8] = P.v;
  }
  // ---- prefetch chunk 1 into registers (consumed at ch=0, tt=0)
  float4 pa  = *(const float4*)(xps + CHUNK * INn);
  float4 pb2 = *(const float4*)(xps + CHUNK * INn + 4);

  __syncthreads();  // hbuf zero + xlds[0] visible

  // ---- initial x-gate accumulators (ch=0, tt=0); bias regs as C operand
  half8 a2 = *(const half8*)&xlds[0][0][n * 8];
  floatx4 xi  = __builtin_amdgcn_mfma_f32_16x16x32_f16(a2, bf[0][2], bi,  0, 0, 0);
  floatx4 xfv = __builtin_amdgcn_mfma_f32_16x16x32_f16(a2, bf[1][2], bfv, 0, 0, 0);
  floatx4 xgv = __builtin_amdgcn_mfma_f32_16x16x32_f16(a2, bf[2][2], bg,  0, 0, 0);
  floatx4 xo  = __builtin_amdgcn_mfma_f32_16x16x32_f16(a2, bf[3][2], bo,  0, 0, 0);

  floatx2 chat01 = {0.f, 0.f};  // scaled cell state, rows q*4+{0,1}
  floatx2 chat23 = {0.f, 0.f};  // rows q*4+{2,3}

  for (int ch = 0; ch < NCHUNK; ++ch) {
    #pragma unroll
    for (int tt = 0; tt < CHUNK; ++tt) {
      const int p  = tt & 1;
      const int pn = p ^ 1;

      // post-barrier critical chain: h fragments + 2 dependent MFMAs per gate
      const half8 a0 = *(const half8*)&hbuf[p][n][q * 8];
      const half8 a1 = *(const half8*)&hbuf[p][n][32 + q * 8];

      floatx4 ai = __builtin_amdgcn_mfma_f32_16x16x32_f16(a0, bf[0][0], xi,  0, 0, 0);
      floatx4 af = __builtin_amdgcn_mfma_f32_16x16x32_f16(a0, bf[1][0], xfv, 0, 0, 0);
      floatx4 ag = __builtin_amdgcn_mfma_f32_16x16x32_f16(a0, bf[2][0], xgv, 0, 0, 0);
      floatx4 ao = __builtin_amdgcn_mfma_f32_16x16x32_f16(a0, bf[3][0], xo,  0, 0, 0);
      ai = __builtin_amdgcn_mfma_f32_16x16x32_f16(a1, bf[0][1], ai, 0, 0, 0);
      af = __builtin_amdgcn_mfma_f32_16x16x32_f16(a1, bf[1][1], af, 0, 0, 0);
      ag = __builtin_amdgcn_mfma_f32_16x16x32_f16(a1, bf[2][1], ag, 0, 0, 0);
      ao = __builtin_amdgcn_mfma_f32_16x16x32_f16(a1, bf[3][1], ao, 0, 0, 0);

      // off-critical-path work, hidden under MFMA/act latency:
      if (tt == 0) {
        // publish next chunk's x into the opposite parity buffer; the regular
        // step barrier publishes it (last read of that buffer was >=2 barriers
        // ago). pa/pb2 hold chunk ch+1 here.
        union { half8 v; fp16x2 h2[4]; } P;
        P.h2[0] = __builtin_amdgcn_cvt_pkrtz(pa.x, pa.y);
        P.h2[1] = __builtin_amdgcn_cvt_pkrtz(pa.z, pa.w);
        P.h2[2] = __builtin_amdgcn_cvt_pkrtz(pb2.x, pb2.y);
        P.h2[3] = __builtin_amdgcn_cvt_pkrtz(pb2.z, pb2.w);
        *(half8*)&xlds[(ch + 1) & 1][tt_s][row_s * 8] = P.v;
      }
      if (tt == 1) {
        // reissue global prefetch (chunk ch+2, wrapped); consumed 15 steps later
        const int chn = (ch + 2 < NCHUNK) ? (ch + 2) : 0;
        pa  = *(const float4*)(xps + (size_t)chn * CHUNK * INn);
        pb2 = *(const float4*)(xps + (size_t)chn * CHUNK * INn + 4);
      }

      const floatx2 h01 = act_pair(ai[0], ai[1], af[0], af[1],
                                   ag[0], ag[1], ao[0], ao[1], chat01);
      hbuf[pn][q * 4 + 0][u] = (f16_t)h01.x;
      hbuf[pn][q * 4 + 1][u] = (f16_t)h01.y;
      const floatx2 h23 = act_pair(ai[2], ai[3], af[2], af[3],
                                   ag[2], ag[3], ao[2], ao[3], chat23);
      hbuf[pn][q * 4 + 2][u] = (f16_t)h23.x;
      hbuf[pn][q * 4 + 3][u] = (f16_t)h23.y;

      // next step's x-gate accumulators, issued in the barrier shadow.
      // tt<15: same chunk, tt+1.  tt==15: next chunk's buffer, tt=0 (written
      // at this chunk's tt==0, published 15 barriers ago). Last iteration
      // computes harmless garbage (never consumed).
      {
        const int nbuf = (tt == CHUNK - 1) ? ((ch + 1) & 1) : (ch & 1);
        const int ntt  = (tt + 1) & (CHUNK - 1);
        a2 = *(const half8*)&xlds[nbuf][ntt][n * 8];
        xi  = __builtin_amdgcn_mfma_f32_16x16x32_f16(a2, bf[0][2], bi,  0, 0, 0);
        xfv = __builtin_amdgcn_mfma_f32_16x16x32_f16(a2, bf[1][2], bfv, 0, 0, 0);
        xgv = __builtin_amdgcn_mfma_f32_16x16x32_f16(a2, bf[2][2], bg,  0, 0, 0);
        xo  = __builtin_amdgcn_mfma_f32_16x16x32_f16(a2, bf[3][2], bo,  0, 0, 0);
      }

      __syncthreads();
    }
  }

  // ---- epilogue: out[b] = h_T[b,:] . W_fc + b_fc   (h_T is in hbuf[0])
  if (tid < 64) {
    const int b = lane & 15;
    const int part = lane >> 4;
    float s = 0.f;
    #pragma unroll
    for (int k = 0; k < 16; ++k) {
      const int uu = part * 16 + k;
      s = __builtin_fmaf((float)hbuf[0][b][uu], W_fc[uu], s);
    }
    s += __shfl_down(s, 32);
    s += __shfl_down(s, 16);
    if (lane < 16) out[bbase + b] = s + b_fc[0];
  }
}

extern "C" void kernel_launch(void* const* d_in, const int* in_sizes, int n_in,
                              void* d_out, int out_size, void* d_ws, size_t ws_size,
                              hipStream_t stream) {
  const float* x    = (const float*)d_in[0];
  const float* W_ih = (const float*)d_in[1];
  const float* W_hh = (const float*)d_in[2];
  const float* b_ih = (const float*)d_in[3];
  const float* b_hh = (const float*)d_in[4];
  const float* W_fc = (const float*)d_in[5];
  const float* b_fc = (const float*)d_in[6];
  float* out = (float*)d_out;
  dim3 grid(Bn / BT), block(256);
  hipLaunchKernelGGL(lstm_fused, grid, block, 0, stream,
                     x, W_ih, W_hh, b_ih, b_hh, W_fc, b_fc, out);
}